// Round 1
// baseline (1652.589 us; speedup 1.0000x reference)
//
#include <hip/hip_runtime.h>

// HH + synapse constants (match reference exactly)
#define B_ 16
#define N_ 2000
#define L_ 1024

__global__ __launch_bounds__(64) void hh_kernel(const float* __restrict__ z,
                                                float* __restrict__ out) {
    const int tid = blockIdx.x * 64 + threadIdx.x;   // 0 .. B*L-1
    const int b = tid >> 10;                          // L = 1024
    const int l = tid & 1023;
    const int base = b * (N_ * L_) + l;

    const float DT  = 0.02f;
    const float DT2 = 0.01f;      // DT/2
    const float GNA = 40.0f, GK = 35.0f, GL = 0.3f;
    const float ENA = 55.0f, EK = -77.0f, EL = -65.0f;
    const float IAPP = 1.0f;
    const float A_R = 0.1f;

    float V = -70.0f, m = 0.0f, n = 0.0f, h = 1.0f, y = 0.0f;

    // out[b,0,l] = sigmoid((V0 - VT)/KP),  VT=-20, KP=3
    out[base] = 1.0f / (1.0f + expf(-((V + 20.0f) / 3.0f)));

    float zc = z[base];   // z[b,0,l], consumed by step k=1
    for (int k = 1; k < N_; ++k) {
        // prefetch z for the next step (z[b,k,l] consumed at step k+1)
        float znext = 0.0f;
        if (k < N_ - 1) znext = z[base + k * L_];

        // --- implicit-ish HH voltage update ---
        float m3   = m * m * m;
        float n2   = n * n;
        float pow1 = GNA * m3 * h;
        float pow2 = GK * n2 * n2;
        float G = DT2 * (pow1 + pow2 + GL + y);          // GS = 1
        float E = pow1 * ENA + pow2 * EK + GL * EL;      // GS*VS*y = 0
        float Vn = (V * (1.0f - G) + DT * (E + IAPP)) / (1.0f + G);

        // --- rate constants (singularity-patched like the reference) ---
        bool at25  = (Vn == 25.0f);
        bool atm35 = (Vn == -35.0f);
        float dN  = 1.0f - expf((-Vn + 25.0f) / 9.0f);
        float dM  = 1.0f - expf((-Vn - 35.0f) / 9.0f);
        float dNb = 1.0f - expf((Vn - 25.0f) / 9.0f);
        float dMb = 1.0f - expf((Vn + 35.0f) / 9.0f);
        float aN = at25  ? 0.18f  :  0.02f  * (Vn - 25.0f) / dN;
        float bN = at25  ? 0.08f  : -0.002f * (Vn - 25.0f) / dNb;
        float aM = atm35 ? 1.638f :  0.182f * (Vn + 35.0f) / dM;
        float bM = atm35 ? 1.16f  : -0.124f * (Vn + 35.0f) / dMb;
        float aH = 0.25f * expf((-Vn - 90.0f) / 12.0f);
        float bH = 0.25f * expf((Vn + 34.0f) / 12.0f);

        // --- gate updates (Crank–Nicolson style, as in reference) ---
        float sM = DT2 * (aM + bM);
        m = (aM * DT + (1.0f - sM) * m) / (sM + 1.0f);
        float sN = DT2 * (aN + bN);
        n = (aN * DT + (1.0f - sN) * n) / (sN + 1.0f);
        float sH = DT2 * (aH + bH);
        h = (aH * DT + (1.0f - sH) * h) / (sH + 1.0f);

        // --- synapse update driven by z[k-1] ---
        float ady = zc;                                  // A_D = 1
        float sY = DT2 * (ady + A_R);
        y = (ady * DT + (1.0f - sY) * y) / (sY + 1.0f);

        V = Vn;
        out[base + k * L_] = 1.0f / (1.0f + expf(-((V + 20.0f) / 3.0f)));
        zc = znext;
    }
}

extern "C" void kernel_launch(void* const* d_in, const int* in_sizes, int n_in,
                              void* d_out, int out_size, void* d_ws, size_t ws_size,
                              hipStream_t stream) {
    const float* z = (const float*)d_in[0];
    float* out = (float*)d_out;
    // 16384 chains, 64 threads/block -> 256 blocks (1 wave per CU)
    hh_kernel<<<256, 64, 0, stream>>>(z, out);
}

// Round 2
// 1353.410 us; speedup vs baseline: 1.2211x; 1.2211x over previous
//
#include <hip/hip_runtime.h>

#define N_ 2000
#define L_ 1024

// v_exp_f32-based exp: 2 instructions, ~1 ulp
__device__ __forceinline__ float fast_exp(float x) { return __expf(x); }

// rcp + 1 Newton iteration: ~1.5 ulp divide, 1 trans + 3 VALU
__device__ __forceinline__ float fast_div(float num, float d) {
    float r = __builtin_amdgcn_rcpf(d);
    r = r * __fmaf_rn(-d, r, 2.0f);
    return num * r;
}

__global__ __launch_bounds__(64) void hh_kernel(const float* __restrict__ z,
                                                float* __restrict__ out) {
    const int tid = blockIdx.x * 64 + threadIdx.x;   // 0 .. B*L-1
    const int b = tid >> 10;                          // L = 1024
    const int l = tid & 1023;
    const int base = b * (N_ * L_) + l;               // max ~32.7M, fits int

    const float DT  = 0.02f;
    const float DT2 = 0.01f;      // DT/2
    const float GNA = 40.0f, GK = 35.0f, GL = 0.3f;
    const float ENA = 55.0f, EK = -77.0f, EL = -65.0f;
    const float IAPP = 1.0f;
    const float A_R = 0.1f;
    const float INV9  = 1.0f / 9.0f;
    const float INV12 = 1.0f / 12.0f;
    const float INV3  = 1.0f / 3.0f;

    float V = -70.0f, m = 0.0f, n = 0.0f, h = 1.0f, y = 0.0f;

    // out[b,0,l] = sigmoid((V0 + 20)/3)
    {
        float e0 = fast_exp(-(V + 20.0f) * INV3);
        out[base] = __builtin_amdgcn_rcpf(1.0f + e0);
    }

    // 4-deep prefetch ring for z (step k consumes z[k-1])
    float zb[4];
    zb[0] = z[base];
    zb[1] = z[base + 1 * L_];
    zb[2] = z[base + 2 * L_];
    zb[3] = z[base + 3 * L_];

#pragma unroll 4
    for (int k = 1; k < N_; ++k) {
        float zc = zb[(k - 1) & 3];
        int kpre = k + 3;                     // consumed at step kpre+1
        if (kpre < N_ - 1) zb[kpre & 3] = z[base + kpre * L_];

        // --- voltage update ---
        float m3   = m * m * m;
        float n2   = n * n;
        float pow1 = GNA * m3 * h;
        float pow2 = GK * n2 * n2;
        float G = DT2 * (pow1 + pow2 + GL + y);          // GS = 1
        float E = pow1 * ENA + pow2 * EK + GL * EL;      // GS*VS*y = 0
        float Vn = fast_div(V * (1.0f - G) + DT * (E + IAPP), 1.0f + G);

        // --- rate constants (singularity-patched exactly like reference) ---
        bool at25  = (Vn == 25.0f);
        bool atm35 = (Vn == -35.0f);
        float dN  = 1.0f - fast_exp((25.0f - Vn) * INV9);
        float dM  = 1.0f - fast_exp((-Vn - 35.0f) * INV9);
        float dNb = 1.0f - fast_exp((Vn - 25.0f) * INV9);
        float dMb = 1.0f - fast_exp((Vn + 35.0f) * INV9);
        float aN = at25  ? 0.18f  : fast_div( 0.02f  * (Vn - 25.0f), dN);
        float bN = at25  ? 0.08f  : fast_div(-0.002f * (Vn - 25.0f), dNb);
        float aM = atm35 ? 1.638f : fast_div( 0.182f * (Vn + 35.0f), dM);
        float bM = atm35 ? 1.16f  : fast_div(-0.124f * (Vn + 35.0f), dMb);
        float aH = 0.25f * fast_exp((-Vn - 90.0f) * INV12);
        float bH = 0.25f * fast_exp((Vn + 34.0f) * INV12);

        // --- gate updates ---
        float sM = DT2 * (aM + bM);
        m = fast_div(__fmaf_rn(aM, DT, (1.0f - sM) * m), sM + 1.0f);
        float sN = DT2 * (aN + bN);
        n = fast_div(__fmaf_rn(aN, DT, (1.0f - sN) * n), sN + 1.0f);
        float sH = DT2 * (aH + bH);
        h = fast_div(__fmaf_rn(aH, DT, (1.0f - sH) * h), sH + 1.0f);

        // --- synapse update driven by z[k-1] ---
        float sY = DT2 * (zc + A_R);                     // A_D = 1
        y = fast_div(__fmaf_rn(zc, DT, (1.0f - sY) * y), sY + 1.0f);

        V = Vn;
        float e = fast_exp(-(V + 20.0f) * INV3);
        out[base + k * L_] = __builtin_amdgcn_rcpf(1.0f + e);
    }
}

extern "C" void kernel_launch(void* const* d_in, const int* in_sizes, int n_in,
                              void* d_out, int out_size, void* d_ws, size_t ws_size,
                              hipStream_t stream) {
    const float* z = (const float*)d_in[0];
    float* out = (float*)d_out;
    // 16384 chains, 64 threads/block -> 256 blocks (1 wave per CU)
    hh_kernel<<<256, 64, 0, stream>>>(z, out);
}

// Round 3
// 606.292 us; speedup vs baseline: 2.7257x; 2.2323x over previous
//
#include <hip/hip_runtime.h>

#define N_ 2000
#define L_ 1024

// v_exp_f32 directly (exp2). Hedge in case the builtin is unavailable.
#if defined(__has_builtin)
#  if __has_builtin(__builtin_amdgcn_exp2f)
#    define EXP2F(x) __builtin_amdgcn_exp2f(x)
#  else
#    define EXP2F(x) exp2f(x)
#  endif
#else
#  define EXP2F(x) exp2f(x)
#endif

__device__ __forceinline__ float fast_rcp(float d) {
    return __builtin_amdgcn_rcpf(d);   // ~1 ulp, no Newton
}

__global__ __launch_bounds__(64) void hh_kernel(const float* __restrict__ z,
                                                float* __restrict__ out) {
    const int tid = blockIdx.x * 64 + threadIdx.x;   // 0 .. B*L-1
    const int b = tid >> 10;                          // L = 1024
    const int l = tid & 1023;
    const int base = b * (N_ * L_) + l;

    const float DT  = 0.02f;
    const float DT2 = 0.01f;                 // DT/2
    const float GL  = 0.3f;
    // log2(e)/9, log2(e)/12, log2(e)/3
    const float K9  = 0.16029944898766259f;
    const float K12 = 0.12022458674074695f;
    const float K3  = 0.48089834696298783f;

    float V = -70.0f, m = 0.0f, n = 0.0f, h = 1.0f, y = 0.0f;

    // out[b,0,l] = sigmoid((V0 + 20)/3)
    out[base] = fast_rcp(1.0f + EXP2F(-(V + 20.0f) * K3));

    // 8-deep prefetch ring: zb slot holds z consumed 8 steps later
    float zb[8];
#pragma unroll
    for (int i = 0; i < 8; ++i) zb[i] = z[base + i * L_];

#pragma unroll 8
    for (int k = 1; k < N_; ++k) {
        float zc = zb[(k - 1) & 7];
        int kpre = k + 7;                          // consumed at step k+8
        int kc = kpre < 1998 ? kpre : 1998;        // branchless clamp, always valid
        zb[(k - 1) & 7] = z[base + kc * L_];

        // --- voltage update ---
        float m3   = m * m * m;
        float n2   = n * n;
        float pow1 = 40.0f * (m3 * h);             // GNA
        float pow2 = 35.0f * (n2 * n2);            // GK
        float G = DT2 * (pow1 + pow2 + (GL + y));  // GS = 1
        // E = pow1*ENA + pow2*EK + GL*EL  (GS*VS*y = 0)
        float E = __fmaf_rn(pow1, 55.0f, __fmaf_rn(pow2, -77.0f, -19.5f));
        float num = __fmaf_rn(V, 1.0f - G, DT * (E + 1.0f));
        float Vn  = num * fast_rcp(1.0f + G);

        // --- rates, algebraically paired (one exp + one rcp per pair) ---
        bool at25  = (Vn == 25.0f);
        bool atm35 = (Vn == -35.0f);

        float u  = Vn - 25.0f;
        float e1 = EXP2F(u * K9);                  // exp((Vn-25)/9)
        float r1 = fast_rcp(e1 - 1.0f);
        float ur1 = u * r1;
        float aN = at25 ? 0.18f : 0.02f * (ur1 * e1);
        float bN = at25 ? 0.08f : 0.002f * ur1;

        float v  = Vn + 35.0f;
        float e2 = EXP2F(v * K9);                  // exp((Vn+35)/9)
        float r2 = fast_rcp(e2 - 1.0f);
        float vr2 = v * r2;
        float aM = atm35 ? 1.638f : 0.182f * (vr2 * e2);
        float bM = atm35 ? 1.16f  : 0.124f * vr2;

        float aH = 0.25f * EXP2F(-(Vn + 90.0f) * K12);
        float bH = 0.25f * EXP2F( (Vn + 34.0f) * K12);

        // --- gate updates ---
        float sM = DT2 * (aM + bM);
        m = __fmaf_rn(aM, DT, __fmaf_rn(-sM, m, m)) * fast_rcp(1.0f + sM);
        float sN = DT2 * (aN + bN);
        n = __fmaf_rn(aN, DT, __fmaf_rn(-sN, n, n)) * fast_rcp(1.0f + sN);
        float sH = DT2 * (aH + bH);
        h = __fmaf_rn(aH, DT, __fmaf_rn(-sH, h, h)) * fast_rcp(1.0f + sH);

        // --- synapse (A_D = 1, A_R = 0.1) ---
        float sY = DT2 * (zc + 0.1f);
        y = __fmaf_rn(zc, DT, __fmaf_rn(-sY, y, y)) * fast_rcp(1.0f + sY);

        V = Vn;
        out[base + k * L_] = fast_rcp(1.0f + EXP2F(-(V + 20.0f) * K3));
    }
}

extern "C" void kernel_launch(void* const* d_in, const int* in_sizes, int n_in,
                              void* d_out, int out_size, void* d_ws, size_t ws_size,
                              hipStream_t stream) {
    const float* z = (const float*)d_in[0];
    float* out = (float*)d_out;
    // 16384 chains, 64 threads/block -> 256 blocks (1 wave per CU)
    hh_kernel<<<256, 64, 0, stream>>>(z, out);
}

// Round 4
// 566.124 us; speedup vs baseline: 2.9191x; 1.0710x over previous
//
#include <hip/hip_runtime.h>

#define N_ 2000
#define L_ 1024

__device__ __forceinline__ float rcpf(float d) { return __builtin_amdgcn_rcpf(d); }
__device__ __forceinline__ float ex2(float x)  { return __builtin_amdgcn_exp2f(x); }

// One chain per LANE-PAIR: even lane = M-rates + gates (m,h); odd = N-rates + gates (n,y).
// STEP2: K = timestep (consumes z[K-1], writes out rows K-1,K on store phases),
//        RS = compile-time ring slot = (K-1)&7.
#define STEP2(K, RS, DOSTORE)                                                 \
  {                                                                           \
    const int kk = (K);                                                       \
    float zc = zb[RS];                                                        \
    int kpre = kk + 7;                                                        \
    int kc = kpre < 1998 ? kpre : 1998;                                       \
    zb[RS] = z[base + kc * L_];                                               \
    /* Vn partials: val = m^3*h (even) | n^4 (odd) */                         \
    float w    = evn ? sB : sA;                                               \
    float t1   = sA * sA;                                                     \
    float val  = (t1 * sA) * w;                                               \
    float gAdd = evn ? 0.003f : 0.01f * sB;   /* GL*DT2 | DT2*y */            \
    float Gh   = __fmaf_rn(val, cG, gAdd);                                    \
    float Eh   = __fmaf_rn(val, cE, eAdd);                                    \
    float G    = Gh + __shfl_xor(Gh, 1, 64);                                  \
    float E    = Eh + __shfl_xor(Eh, 1, 64);                                  \
    float num  = __fmaf_rn(V, 1.0f - G, 0.02f * (E + 1.0f));                  \
    float Vn   = num * rcpf(1.0f + G);                                        \
    /* rates: shared e1 = exp((Vn-25)/9); even derives e2 = C60*e1 */         \
    float e1   = ex2(__fmaf_rn(Vn, K9, -25.0f * K9));                         \
    float eR   = e1 * cm;                                                     \
    float u    = Vn + cu;                                                     \
    float r    = rcpf(eR - 1.0f);                                             \
    float ur   = u * r;                                                       \
    bool  pat  = (Vn == cc);                                                  \
    float av   = pat ? pa : ka * (ur * eR);                                   \
    float bv   = pat ? pb : kb * ur;                                          \
    /* H-exps: even computes aH, odd computes bH; swap bH to even */          \
    float vH   = 0.25f * ex2(__fmaf_rn(Vn, sHc, cHc));                        \
    float vHx  = __shfl_xor(vH, 1, 64);                                       \
    /* gate slot 1: m (even) | n (odd) */                                     \
    float s1   = __fmaf_rn(av, 0.01f, 0.01f * bv);                            \
    float q1   = 1.0f + s1;                                                   \
    float num1 = __fmaf_rn(av, 0.02f, __fmaf_rn(-s1, sA, sA));                \
    /* gate slot 2: h (even) | y (odd) */                                     \
    float a2   = evn ? vH  : zc;                                              \
    float b2   = evn ? vHx : 0.1f;                                            \
    float s2   = __fmaf_rn(a2, 0.01f, 0.01f * b2);                            \
    float q2   = 1.0f + s2;                                                   \
    float num2 = __fmaf_rn(a2, 0.02f, __fmaf_rn(-s2, sB, sB));                \
    float rq   = rcpf(q1 * q2);                                               \
    sA = num1 * (rq * q2);                                                    \
    sB = num2 * (rq * q1);                                                    \
    V = Vn;                                                                   \
    if (DOSTORE) {                                                            \
      /* lanes split output rows K-1 (even, via e1p) and K (odd, via e1) */   \
      float esel = evn ? e1p : e1;                                            \
      float e3 = (esel * esel) * esel;                                        \
      float ts = e3 * C15;              /* = exp((V+20)/3) */                 \
      float sg = ts * rcpf(1.0f + ts);                                        \
      out[base + (kk - 1 + sub) * L_] = sg;                                   \
    } else {                                                                  \
      e1p = e1;                                                               \
    }                                                                         \
  }

__global__ __launch_bounds__(64) void hh_kernel(const float* __restrict__ z,
                                                float* __restrict__ out) {
    const int t   = blockIdx.x * 64 + threadIdx.x;   // 0 .. 32767
    const int sub = t & 1;
    const int ch  = t >> 1;                           // chain 0..16383
    const int b   = ch >> 10;
    const int l   = ch & 1023;
    const int base = b * (N_ * L_) + l;

    const bool evn = (sub == 0);

    const float K9  = 0.16029944898766259f;   // log2(e)/9
    const float K12 = 0.12022458674074695f;   // log2(e)/12
    const float C60 = 785.77207f;             // e^(60/9): e2 = C60*e1
    const float C15 = 3269017.37f;            // e^15: sigmoid arg from e1^3

    // per-lane constants (loop-invariant registers)
    const float cG   = evn ? 0.4f      : 0.35f;     // DT2*GNA | DT2*GK
    const float cE   = evn ? 2200.0f   : -2695.0f;  // GNA*ENA | GK*EK
    const float eAdd = evn ? -19.5f    : 0.0f;      // GL*EL   | 0
    const float cu   = evn ? 35.0f     : -25.0f;    // u = Vn + cu
    const float cm   = evn ? C60       : 1.0f;      // eR = cm*e1 (e2 | e1)
    const float cc   = evn ? -35.0f    : 25.0f;     // singularity compare
    const float ka   = evn ? 0.182f    : 0.02f;
    const float kb   = evn ? 0.124f    : 0.002f;
    const float pa   = evn ? 1.638f    : 0.18f;
    const float pb   = evn ? 1.16f     : 0.08f;
    const float sHc  = evn ? -K12      : K12;       // argH = sHc*Vn + cHc
    const float cHc  = evn ? -90.0f*K12 : 34.0f*K12;

    float V  = -70.0f;
    float sA = 0.0f;                 // m | n
    float sB = evn ? 1.0f : 0.0f;    // h | y
    float e1p = ex2((-70.0f - 25.0f) * K9);   // e1 of initial state (step 0)

    float zb[8];
#pragma unroll
    for (int i = 0; i < 8; ++i) zb[i] = z[base + i * L_];

    // pair-steps: odd K stores rows (K-1, K); even K saves e1p.
    int k2 = 1;
    for (int g = 0; g < 249; ++g) {          // K = 1 .. 1992
#pragma unroll
        for (int j = 0; j < 4; ++j) {
            STEP2(k2 + 2 * j,     2 * j,     true)
            STEP2(k2 + 2 * j + 1, 2 * j + 1, false)
        }
        k2 += 8;
    }
    // k2 == 1993: remaining pairs K=1993..1998, then K=1999
#pragma unroll
    for (int j = 0; j < 3; ++j) {
        STEP2(k2 + 2 * j,     2 * j,     true)
        STEP2(k2 + 2 * j + 1, 2 * j + 1, false)
    }
    STEP2(1999, 6, true)
}

extern "C" void kernel_launch(void* const* d_in, const int* in_sizes, int n_in,
                              void* d_out, int out_size, void* d_ws, size_t ws_size,
                              hipStream_t stream) {
    const float* z = (const float*)d_in[0];
    float* out = (float*)d_out;
    // 16384 chains x 2 lanes = 32768 threads = 512 waves (2 per CU)
    hh_kernel<<<512, 64, 0, stream>>>(z, out);
}